// Round 10
// baseline (2136.055 us; speedup 1.0000x reference)
//
// v5: = v4 with scan __launch_bounds__(64,1) so the register allocator can keep
// the depth-4 prefetch distance (v4 capped at 196 VGPR and sank the loads).
#include <hip/hip_runtime.h>
#include <math.h>

#define BB   8
#define TT   2048
#define DD   544
#define HH   8
#define DKK  64
#define DVV  128
#define KD   512
#define VD   1024
#define HIDD 1632
#define MTOK (BB*TT)

// ---------------- workspace layout (floats), total 50,626,560 fl = 202.5 MB ----
static const size_t OFF_R1   = 0;
static const size_t OFF_R2   = 16384;
static const size_t OFF_BETA = 32768;
static const size_t OFF_G    = 163840;
static const size_t OFF_PPRE = 294912;
static const size_t OFF_QBUF = OFF_PPRE + 16777216;
static const size_t OFF_KBUF = OFF_QBUF + 8388608;
static const size_t OFF_VBUF = OFF_KBUF + 8388608;
static const size_t WS_FLOATS = OFF_VBUF + 16777216;
// aliases: obuf=PPRE; gate=QBUF..KBUF; xmid=VBUF; m2=PPRE.. (ends 27.0M < 33.8M xmid)

typedef short     bf16x8  __attribute__((ext_vector_type(8)));
typedef unsigned short ushort8 __attribute__((ext_vector_type(8)));
typedef float     f32x4   __attribute__((ext_vector_type(4)));

__device__ inline unsigned short f2bf(float f) {
    unsigned u = __builtin_bit_cast(unsigned, f);
    u += 0x7FFF + ((u >> 16) & 1);
    return (unsigned short)(u >> 16);
}
__device__ inline float bf2f(unsigned short h) {
    unsigned u = ((unsigned)h) << 16;
    return __builtin_bit_cast(float, u);
}

// ---------------- small kernels (unchanged) ----------------

__global__ __launch_bounds__(256)
void rms_scale_kernel(const float* __restrict__ x, float* __restrict__ r, float eps) {
    __shared__ float red[4];
    const int tok  = blockIdx.x;
    const int lane = threadIdx.x & 63, wid = threadIdx.x >> 6;
    const float* xr = x + (size_t)tok * DD;
    float ss = 0.f;
    for (int c = threadIdx.x; c < DD; c += 256) { float v = xr[c]; ss = fmaf(v, v, ss); }
#pragma unroll
    for (int off = 32; off > 0; off >>= 1) ss += __shfl_xor(ss, off);
    if (lane == 0) red[wid] = ss;
    __syncthreads();
    if (threadIdx.x == 0)
        r[tok] = rsqrtf((red[0] + red[1] + red[2] + red[3]) * (1.0f / DD) + eps);
}

__global__ __launch_bounds__(256)
void proj_bg_kernel(const float* __restrict__ x, const float* __restrict__ r1,
                    const float* __restrict__ Wb, const float* __restrict__ Wa,
                    const float* __restrict__ A_log, const float* __restrict__ dt_bias,
                    float* __restrict__ beta, float* __restrict__ g) {
    const int wave = (blockIdx.x * 256 + threadIdx.x) >> 6;
    const int lane = threadIdx.x & 63;
    const float rr = r1[wave];
    const float* hr = x + (size_t)wave * DD;
    float hv[9];
#pragma unroll
    for (int i = 0; i < 8; ++i) hv[i] = hr[lane + 64 * i] * rr;
    hv[8] = (lane < 32) ? hr[lane + 512] * rr : 0.f;
    for (int j = 0; j < HH; ++j) {
        float sb = 0.f, sa = 0.f;
#pragma unroll
        for (int i = 0; i < 8; ++i) {
            sb = fmaf(hv[i], Wb[j * DD + lane + 64 * i], sb);
            sa = fmaf(hv[i], Wa[j * DD + lane + 64 * i], sa);
        }
        if (lane < 32) {
            sb = fmaf(hv[8], Wb[j * DD + lane + 512], sb);
            sa = fmaf(hv[8], Wa[j * DD + lane + 512], sa);
        }
#pragma unroll
        for (int off = 32; off > 0; off >>= 1) { sb += __shfl_xor(sb, off); sa += __shfl_xor(sa, off); }
        if (lane == 0) {
            beta[(size_t)wave * HH + j] = 2.f / (1.f + expf(-sb));
            const float xg = sa + dt_bias[j];
            const float sp = fmaxf(xg, 0.f) + log1pf(expf(-fabsf(xg)));
            g[(size_t)wave * HH + j] = -expf(A_log[j]) * sp;
        }
    }
}

__global__ __launch_bounds__(256)
void conv_silu_kernel(const float* __restrict__ xin, const float* __restrict__ w,
                      float* __restrict__ y, int C) {
    const int c  = blockIdx.x * 256 + threadIdx.x;
    const int b  = blockIdx.y;
    const int t0 = blockIdx.z * 128;
    const float* xp = xin + (size_t)b * TT * C + c;
    float*       yp = y   + (size_t)b * TT * C + c;
    const float w0 = w[c * 4 + 0], w1 = w[c * 4 + 1], w2 = w[c * 4 + 2], w3 = w[c * 4 + 3];
    float xm3 = (t0 >= 3) ? xp[(size_t)(t0 - 3) * C] : 0.f;
    float xm2 = (t0 >= 2) ? xp[(size_t)(t0 - 2) * C] : 0.f;
    float xm1 = (t0 >= 1) ? xp[(size_t)(t0 - 1) * C] : 0.f;
    for (int t = t0; t < t0 + 128; ++t) {
        const float xc = xp[(size_t)t * C];
        const float u  = fmaf(xm3, w0, fmaf(xm2, w1, fmaf(xm1, w2, xc * w3)));
        yp[(size_t)t * C] = u / (1.f + expf(-u));
        xm3 = xm2; xm2 = xm1; xm1 = xc;
    }
}

__global__ __launch_bounds__(256)
void l2norm_kernel(float* __restrict__ p, float scale) {
    const int row  = (blockIdx.x * 256 + threadIdx.x) >> 6;
    const int lane = threadIdx.x & 63;
    float* r = p + (size_t)row * 64;
    const float v = r[lane];
    float ss = v * v;
#pragma unroll
    for (int off = 32; off > 0; off >>= 1) ss += __shfl_xor(ss, off);
    r[lane] = v * rsqrtf(ss + 1e-6f) * scale;
}

__global__ __launch_bounds__(256)
void onorm_kernel(float* __restrict__ o, const float* __restrict__ gate,
                  const float* __restrict__ w) {
    const int row  = (blockIdx.x * 256 + threadIdx.x) >> 6;
    const int lane = threadIdx.x & 63;
    float*       op = o    + (size_t)row * DVV;
    const float* gp = gate + (size_t)row * DVV;
    const float v0 = op[lane], v1 = op[lane + 64];
    float ss = fmaf(v0, v0, v1 * v1);
#pragma unroll
    for (int off = 32; off > 0; off >>= 1) ss += __shfl_xor(ss, off);
    const float r  = rsqrtf(ss * (1.0f / DVV) + 1e-5f);
    const float g0 = gp[lane], g1 = gp[lane + 64];
    op[lane]      = v0 * r * w[lane]      * (g0 / (1.f + expf(-g0)));
    op[lane + 64] = v1 * r * w[lane + 64] * (g1 / (1.f + expf(-g1)));
}

// ---------------- bf16x3 MFMA GEMM (unchanged from v4) ----------------
template <int EPI>   // 0: C=acc ; 1: C=res+scale[n]*acc ; 2: C=relu(acc)^2
__global__ __launch_bounds__(256)
void gemm_bf3(const float* __restrict__ A, const float* __restrict__ Bw,
              float* __restrict__ C, const float* __restrict__ res,
              const float* __restrict__ scale, const float* __restrict__ rs,
              int M, int N, int K) {
    __shared__ unsigned short Ah[128][40];
    __shared__ unsigned short Al[128][40];
    __shared__ unsigned short Bh[128][40];
    __shared__ unsigned short Bl[128][40];

    const int tid = threadIdx.x;
    const int bm = blockIdx.x * 128;
    const int bn = blockIdx.y * 128;

    const int srow = tid >> 1;
    const int skq  = (tid & 1) * 16;
    const float arow = rs ? rs[bm + srow] : 1.0f;
    const float* Ap = A + (size_t)(bm + srow) * K + skq;
    const int brow_g = bn + srow;
    const float* Bp = Bw + (size_t)(brow_g < N ? brow_g : N - 1) * K + skq;

    const int lane = tid & 63, wid = tid >> 6;
    const int wr = wid >> 1, wc = wid & 1;
    const int lm = lane & 15, kg = lane >> 4;

    f32x4 acc[4][4];
#pragma unroll
    for (int i = 0; i < 4; ++i)
#pragma unroll
        for (int j = 0; j < 4; ++j) acc[i][j] = (f32x4){0.f, 0.f, 0.f, 0.f};

    const int nk = K / 32;
    float4 ar0, ar1, ar2, ar3, br0, br1, br2, br3;
    ar0 = *(const float4*)(Ap + 0);  ar1 = *(const float4*)(Ap + 4);
    ar2 = *(const float4*)(Ap + 8);  ar3 = *(const float4*)(Ap + 12);
    br0 = *(const float4*)(Bp + 0);  br1 = *(const float4*)(Bp + 4);
    br2 = *(const float4*)(Bp + 8);  br3 = *(const float4*)(Bp + 12);

    for (int ks = 0; ks < nk; ++ks) {
        __syncthreads();   // prior iter's frag reads done before overwriting LDS
        {
            float f0, f1, f2, f3, f4, f5, f6, f7;
            ushort8 h, l;
            f0 = ar0.x * arow; f1 = ar0.y * arow; f2 = ar0.z * arow; f3 = ar0.w * arow;
            f4 = ar1.x * arow; f5 = ar1.y * arow; f6 = ar1.z * arow; f7 = ar1.w * arow;
            h[0]=f2bf(f0); h[1]=f2bf(f1); h[2]=f2bf(f2); h[3]=f2bf(f3);
            h[4]=f2bf(f4); h[5]=f2bf(f5); h[6]=f2bf(f6); h[7]=f2bf(f7);
            l[0]=f2bf(f0-bf2f(h[0])); l[1]=f2bf(f1-bf2f(h[1])); l[2]=f2bf(f2-bf2f(h[2])); l[3]=f2bf(f3-bf2f(h[3]));
            l[4]=f2bf(f4-bf2f(h[4])); l[5]=f2bf(f5-bf2f(h[5])); l[6]=f2bf(f6-bf2f(h[6])); l[7]=f2bf(f7-bf2f(h[7]));
            *(ushort8*)&Ah[srow][skq] = h; *(ushort8*)&Al[srow][skq] = l;
            f0 = ar2.x * arow; f1 = ar2.y * arow; f2 = ar2.z * arow; f3 = ar2.w * arow;
            f4 = ar3.x * arow; f5 = ar3.y * arow; f6 = ar3.z * arow; f7 = ar3.w * arow;
            h[0]=f2bf(f0); h[1]=f2bf(f1); h[2]=f2bf(f2); h[3]=f2bf(f3);
            h[4]=f2bf(f4); h[5]=f2bf(f5); h[6]=f2bf(f6); h[7]=f2bf(f7);
            l[0]=f2bf(f0-bf2f(h[0])); l[1]=f2bf(f1-bf2f(h[1])); l[2]=f2bf(f2-bf2f(h[2])); l[3]=f2bf(f3-bf2f(h[3]));
            l[4]=f2bf(f4-bf2f(h[4])); l[5]=f2bf(f5-bf2f(h[5])); l[6]=f2bf(f6-bf2f(h[6])); l[7]=f2bf(f7-bf2f(h[7]));
            *(ushort8*)&Ah[srow][skq + 8] = h; *(ushort8*)&Al[srow][skq + 8] = l;
            f0 = br0.x; f1 = br0.y; f2 = br0.z; f3 = br0.w;
            f4 = br1.x; f5 = br1.y; f6 = br1.z; f7 = br1.w;
            h[0]=f2bf(f0); h[1]=f2bf(f1); h[2]=f2bf(f2); h[3]=f2bf(f3);
            h[4]=f2bf(f4); h[5]=f2bf(f5); h[6]=f2bf(f6); h[7]=f2bf(f7);
            l[0]=f2bf(f0-bf2f(h[0])); l[1]=f2bf(f1-bf2f(h[1])); l[2]=f2bf(f2-bf2f(h[2])); l[3]=f2bf(f3-bf2f(h[3]));
            l[4]=f2bf(f4-bf2f(h[4])); l[5]=f2bf(f5-bf2f(h[5])); l[6]=f2bf(f6-bf2f(h[6])); l[7]=f2bf(f7-bf2f(h[7]));
            *(ushort8*)&Bh[srow][skq] = h; *(ushort8*)&Bl[srow][skq] = l;
            f0 = br2.x; f1 = br2.y; f2 = br2.z; f3 = br2.w;
            f4 = br3.x; f5 = br3.y; f6 = br3.z; f7 = br3.w;
            h[0]=f2bf(f0); h[1]=f2bf(f1); h[2]=f2bf(f2); h[3]=f2bf(f3);
            h[4]=f2bf(f4); h[5]=f2bf(f5); h[6]=f2bf(f6); h[7]=f2bf(f7);
            l[0]=f2bf(f0-bf2f(h[0])); l[1]=f2bf(f1-bf2f(h[1])); l[2]=f2bf(f2-bf2f(h[2])); l[3]=f2bf(f3-bf2f(h[3]));
            l[4]=f2bf(f4-bf2f(h[4])); l[5]=f2bf(f5-bf2f(h[5])); l[6]=f2bf(f6-bf2f(h[6])); l[7]=f2bf(f7-bf2f(h[7]));
            *(ushort8*)&Bh[srow][skq + 8] = h; *(ushort8*)&Bl[srow][skq + 8] = l;
        }
        __syncthreads();
        if (ks + 1 < nk) {
            const float* ap = Ap + (ks + 1) * 32;
            const float* bp = Bp + (ks + 1) * 32;
            ar0 = *(const float4*)(ap + 0);  ar1 = *(const float4*)(ap + 4);
            ar2 = *(const float4*)(ap + 8);  ar3 = *(const float4*)(ap + 12);
            br0 = *(const float4*)(bp + 0);  br1 = *(const float4*)(bp + 4);
            br2 = *(const float4*)(bp + 8);  br3 = *(const float4*)(bp + 12);
        }
        bf16x8 fah[4], fal[4], fbh[4], fbl[4];
#pragma unroll
        for (int i = 0; i < 4; ++i) {
            fah[i] = *(const bf16x8*)&Ah[wr * 64 + i * 16 + lm][kg * 8];
            fal[i] = *(const bf16x8*)&Al[wr * 64 + i * 16 + lm][kg * 8];
            fbh[i] = *(const bf16x8*)&Bh[wc * 64 + i * 16 + lm][kg * 8];
            fbl[i] = *(const bf16x8*)&Bl[wc * 64 + i * 16 + lm][kg * 8];
        }
#pragma unroll
        for (int mi = 0; mi < 4; ++mi)
#pragma unroll
            for (int ni = 0; ni < 4; ++ni) {
                acc[mi][ni] = __builtin_amdgcn_mfma_f32_16x16x32_bf16(fal[mi], fbh[ni], acc[mi][ni], 0, 0, 0);
                acc[mi][ni] = __builtin_amdgcn_mfma_f32_16x16x32_bf16(fah[mi], fbl[ni], acc[mi][ni], 0, 0, 0);
                acc[mi][ni] = __builtin_amdgcn_mfma_f32_16x16x32_bf16(fah[mi], fbh[ni], acc[mi][ni], 0, 0, 0);
            }
    }

#pragma unroll
    for (int mi = 0; mi < 4; ++mi)
#pragma unroll
        for (int ni = 0; ni < 4; ++ni) {
            const int n = bn + wc * 64 + ni * 16 + lm;
            if (n < N) {
#pragma unroll
                for (int r = 0; r < 4; ++r) {
                    const int m = bm + wr * 64 + mi * 16 + kg * 4 + r;
                    float v = acc[mi][ni][r];
                    if (EPI == 1)      v = res[(size_t)m * N + n] + scale[n] * v;
                    else if (EPI == 2) { const float t = fmaxf(v, 0.f); v = t * t; }
                    C[(size_t)m * N + n] = v;
                }
            }
        }
}

// ---------------- gated delta-rule scan (depth-4, now with 1-wave/EU reg budget)
// __launch_bounds__(64, 1): min 1 wave/EU -> allocator may use up to 512 VGPRs,
// keeping the ~300-reg live set of the depth-4 rotation WITHOUT sinking the
// refill loads toward their uses (v4 @196 VGPR lost the prefetch distance).
__global__ __launch_bounds__(64, 1)
void scan_kernel(const float* __restrict__ q, const float* __restrict__ k,
                 const float* __restrict__ v, const float* __restrict__ g,
                 const float* __restrict__ beta, float* __restrict__ o) {
    const int bh   = blockIdx.x;
    const int cg   = blockIdx.y;
    const int b    = bh >> 3, hh = bh & 7;
    const int lane = threadIdx.x;
    const int half = lane >> 5;
    const int col  = cg * 32 + (lane & 31);

    const float4* kb = (const float4*)(k + ((size_t)b * TT * HH + hh) * DKK + half * 32);
    const float4* qb = (const float4*)(q + ((size_t)b * TT * HH + hh) * DKK + half * 32);
    const float*  vp = v    + (size_t)b * TT * VD + hh * DVV + col;
    const float*  gp = g    + (size_t)b * TT * HH + hh;
    const float*  bp = beta + (size_t)b * TT * HH + hh;
    float*        op = o    + (size_t)b * TT * VD + hh * DVV + col;

    float S[32];
#pragma unroll
    for (int i = 0; i < 32; ++i) S[i] = 0.f;

    float4 kq4[4][8], qq4[4][8];
    float  eb[4], bb[4], vb[4];
#pragma unroll
    for (int u = 0; u < 4; ++u) {
#pragma unroll
        for (int i = 0; i < 8; ++i) {
            kq4[u][i] = kb[(size_t)u * 128 + i];
            qq4[u][i] = qb[(size_t)u * 128 + i];
        }
        eb[u] = expf(gp[(size_t)u * HH]);
        bb[u] = bp[(size_t)u * HH];
        vb[u] = vp[(size_t)u * VD];
    }

    for (int t4 = 0; t4 < TT; t4 += 4) {
#pragma unroll
        for (int u = 0; u < 4; ++u) {
            const int t = t4 + u;
            float d0 = 0.f, d1 = 0.f, d2 = 0.f, d3 = 0.f;
#pragma unroll
            for (int i = 0; i < 8; ++i) {
                d0 = fmaf(S[4*i+0], kq4[u][i].x, d0);
                d1 = fmaf(S[4*i+1], kq4[u][i].y, d1);
                d2 = fmaf(S[4*i+2], kq4[u][i].z, d2);
                d3 = fmaf(S[4*i+3], kq4[u][i].w, d3);
            }
            float dot = (d0 + d1) + (d2 + d3);
            dot += __shfl_xor(dot, 32);
            const float e = eb[u];
            const float vres = fmaf(-e, dot * bb[u], vb[u] * bb[u]);   // (v - e*dot)*beta
            float o0 = 0.f, o1 = 0.f, o2 = 0.f, o3 = 0.f;
#pragma unroll
            for (int i = 0; i < 8; ++i) {   // S = e*S + k*vres ; out = q^T S
                S[4*i+0] = fmaf(S[4*i+0], e, kq4[u][i].x * vres); o0 = fmaf(S[4*i+0], qq4[u][i].x, o0);
                S[4*i+1] = fmaf(S[4*i+1], e, kq4[u][i].y * vres); o1 = fmaf(S[4*i+1], qq4[u][i].y, o1);
                S[4*i+2] = fmaf(S[4*i+2], e, kq4[u][i].z * vres); o2 = fmaf(S[4*i+2], qq4[u][i].z, o2);
                S[4*i+3] = fmaf(S[4*i+3], e, kq4[u][i].w * vres); o3 = fmaf(S[4*i+3], qq4[u][i].w, o3);
            }
            float outv = (o0 + o1) + (o2 + o3);
            outv += __shfl_xor(outv, 32);
            if (lane < 32) op[(size_t)t * VD] = outv;
            const int tn = (t + 4 < TT) ? t + 4 : TT - 1;
#pragma unroll
            for (int i = 0; i < 8; ++i) {
                kq4[u][i] = kb[(size_t)tn * 128 + i];
                qq4[u][i] = qb[(size_t)tn * 128 + i];
            }
            eb[u] = expf(gp[(size_t)tn * HH]);
            bb[u] = bp[(size_t)tn * HH];
            vb[u] = vp[(size_t)tn * VD];
        }
    }
}

// ---------------- launch ----------------
extern "C" void kernel_launch(void* const* d_in, const int* in_sizes, int n_in,
                              void* d_out, int out_size, void* d_ws, size_t ws_size,
                              hipStream_t stream) {
    const float* x        = (const float*)d_in[0];
    const float* Wq       = (const float*)d_in[1];
    const float* Wk       = (const float*)d_in[2];
    const float* Wv       = (const float*)d_in[3];
    const float* Wb       = (const float*)d_in[4];
    const float* Wa       = (const float*)d_in[5];
    const float* Wg       = (const float*)d_in[6];
    const float* Wo       = (const float*)d_in[7];
    const float* conv_q   = (const float*)d_in[8];
    const float* conv_k   = (const float*)d_in[9];
    const float* conv_v   = (const float*)d_in[10];
    const float* A_log    = (const float*)d_in[11];
    const float* dt_bias  = (const float*)d_in[12];
    const float* o_norm_w = (const float*)d_in[13];
    const float* W_fc     = (const float*)d_in[14];
    const float* W_proj   = (const float*)d_in[15];
    const float* gdn      = (const float*)d_in[16];
    const float* mlps     = (const float*)d_in[17];
    float* out = (float*)d_out;
    float* ws  = (float*)d_ws;

    if (ws_size < WS_FLOATS * sizeof(float)) {
        hipMemsetAsync(d_out, 0, (size_t)out_size * sizeof(float), stream);
        return;
    }

    float* r1    = ws + OFF_R1;
    float* r2    = ws + OFF_R2;
    float* betab = ws + OFF_BETA;
    float* gbuf  = ws + OFF_G;
    float* ppre  = ws + OFF_PPRE;
    float* qbuf  = ws + OFF_QBUF;
    float* kbuf  = ws + OFF_KBUF;
    float* vbuf  = ws + OFF_VBUF;
    float* obuf  = ws + OFF_PPRE;
    float* gateb = ws + OFF_QBUF;
    float* xmid  = ws + OFF_VBUF;
    float* m2    = ws + OFF_PPRE;

    rms_scale_kernel<<<MTOK, 256, 0, stream>>>(x, r1, 1e-6f);
    proj_bg_kernel<<<MTOK / 4, 256, 0, stream>>>(x, r1, Wb, Wa, A_log, dt_bias, betab, gbuf);

    dim3 gqk(MTOK / 128, KD / 128);
    dim3 gvv(MTOK / 128, VD / 128);
    gemm_bf3<0><<<gqk, 256, 0, stream>>>(x, Wq, ppre, nullptr, nullptr, r1, MTOK, KD, DD);
    conv_silu_kernel<<<dim3(KD / 256, BB, TT / 128), 256, 0, stream>>>(ppre, conv_q, qbuf, KD);
    gemm_bf3<0><<<gqk, 256, 0, stream>>>(x, Wk, ppre, nullptr, nullptr, r1, MTOK, KD, DD);
    conv_silu_kernel<<<dim3(KD / 256, BB, TT / 128), 256, 0, stream>>>(ppre, conv_k, kbuf, KD);
    gemm_bf3<0><<<gvv, 256, 0, stream>>>(x, Wv, ppre, nullptr, nullptr, r1, MTOK, VD, DD);
    conv_silu_kernel<<<dim3(VD / 256, BB, TT / 128), 256, 0, stream>>>(ppre, conv_v, vbuf, VD);

    l2norm_kernel<<<(MTOK * HH) / 4, 256, 0, stream>>>(qbuf, 0.125f);
    l2norm_kernel<<<(MTOK * HH) / 4, 256, 0, stream>>>(kbuf, 1.f);

    scan_kernel<<<dim3(64, 4), 64, 0, stream>>>(qbuf, kbuf, vbuf, gbuf, betab, obuf);

    gemm_bf3<0><<<gvv, 256, 0, stream>>>(x, Wg, gateb, nullptr, nullptr, r1, MTOK, VD, DD);
    onorm_kernel<<<(MTOK * HH) / 4, 256, 0, stream>>>(obuf, gateb, o_norm_w);

    dim3 go(MTOK / 128, (DD + 127) / 128);
    gemm_bf3<1><<<go, 256, 0, stream>>>(obuf, Wo, xmid, x, gdn, nullptr, MTOK, DD, VD);

    rms_scale_kernel<<<MTOK, 256, 0, stream>>>(xmid, r2, 1e-6f);
    dim3 gf(MTOK / 128, (HIDD + 127) / 128);
    gemm_bf3<2><<<gf, 256, 0, stream>>>(xmid, W_fc, m2, nullptr, nullptr, r2, MTOK, HIDD, DD);
    dim3 gpj(MTOK / 128, (DD + 127) / 128);
    gemm_bf3<1><<<gpj, 256, 0, stream>>>(m2, W_proj, out, xmid, mlps, nullptr, MTOK, DD, HIDD);

    (void)in_sizes; (void)n_in; (void)ws_size;
}

// Round 11
// 2078.010 us; speedup vs baseline: 1.0279x; 1.0279x over previous
//
// v6: scan rewritten as chunked LDS-staged pipeline (global_load_lds double-buffer,
// 64-step chunks). GEMM/elementwise unchanged from v5 (validated, absmax 0.015625).
#include <hip/hip_runtime.h>
#include <math.h>

#define BB   8
#define TT   2048
#define DD   544
#define HH   8
#define DKK  64
#define DVV  128
#define KD   512
#define VD   1024
#define HIDD 1632
#define MTOK (BB*TT)

// ---------------- workspace layout (floats), total 50,626,560 fl = 202.5 MB ----
static const size_t OFF_R1   = 0;
static const size_t OFF_R2   = 16384;
static const size_t OFF_BETA = 32768;
static const size_t OFF_G    = 163840;
static const size_t OFF_PPRE = 294912;
static const size_t OFF_QBUF = OFF_PPRE + 16777216;
static const size_t OFF_KBUF = OFF_QBUF + 8388608;
static const size_t OFF_VBUF = OFF_KBUF + 8388608;
static const size_t WS_FLOATS = OFF_VBUF + 16777216;
// aliases: obuf=PPRE; gate=QBUF..KBUF; xmid=VBUF; m2=PPRE.. (ends 27.0M < 33.8M xmid)

typedef short     bf16x8  __attribute__((ext_vector_type(8)));
typedef unsigned short ushort8 __attribute__((ext_vector_type(8)));
typedef float     f32x4   __attribute__((ext_vector_type(4)));

__device__ inline unsigned short f2bf(float f) {
    unsigned u = __builtin_bit_cast(unsigned, f);
    u += 0x7FFF + ((u >> 16) & 1);
    return (unsigned short)(u >> 16);
}
__device__ inline float bf2f(unsigned short h) {
    unsigned u = ((unsigned)h) << 16;
    return __builtin_bit_cast(float, u);
}

// async global -> LDS, 4B per lane. Global addr is PER-LANE; LDS dest is
// wave-uniform base + lane*4 (per guide m03/m173).
__device__ inline void gload_lds4(const float* g, float* l) {
    __builtin_amdgcn_global_load_lds(
        (const __attribute__((address_space(1))) float*)g,
        (__attribute__((address_space(3))) float*)l, 4, 0, 0);
}

// ---------------- small kernels (unchanged) ----------------

__global__ __launch_bounds__(256)
void rms_scale_kernel(const float* __restrict__ x, float* __restrict__ r, float eps) {
    __shared__ float red[4];
    const int tok  = blockIdx.x;
    const int lane = threadIdx.x & 63, wid = threadIdx.x >> 6;
    const float* xr = x + (size_t)tok * DD;
    float ss = 0.f;
    for (int c = threadIdx.x; c < DD; c += 256) { float v = xr[c]; ss = fmaf(v, v, ss); }
#pragma unroll
    for (int off = 32; off > 0; off >>= 1) ss += __shfl_xor(ss, off);
    if (lane == 0) red[wid] = ss;
    __syncthreads();
    if (threadIdx.x == 0)
        r[tok] = rsqrtf((red[0] + red[1] + red[2] + red[3]) * (1.0f / DD) + eps);
}

__global__ __launch_bounds__(256)
void proj_bg_kernel(const float* __restrict__ x, const float* __restrict__ r1,
                    const float* __restrict__ Wb, const float* __restrict__ Wa,
                    const float* __restrict__ A_log, const float* __restrict__ dt_bias,
                    float* __restrict__ beta, float* __restrict__ g) {
    const int wave = (blockIdx.x * 256 + threadIdx.x) >> 6;
    const int lane = threadIdx.x & 63;
    const float rr = r1[wave];
    const float* hr = x + (size_t)wave * DD;
    float hv[9];
#pragma unroll
    for (int i = 0; i < 8; ++i) hv[i] = hr[lane + 64 * i] * rr;
    hv[8] = (lane < 32) ? hr[lane + 512] * rr : 0.f;
    for (int j = 0; j < HH; ++j) {
        float sb = 0.f, sa = 0.f;
#pragma unroll
        for (int i = 0; i < 8; ++i) {
            sb = fmaf(hv[i], Wb[j * DD + lane + 64 * i], sb);
            sa = fmaf(hv[i], Wa[j * DD + lane + 64 * i], sa);
        }
        if (lane < 32) {
            sb = fmaf(hv[8], Wb[j * DD + lane + 512], sb);
            sa = fmaf(hv[8], Wa[j * DD + lane + 512], sa);
        }
#pragma unroll
        for (int off = 32; off > 0; off >>= 1) { sb += __shfl_xor(sb, off); sa += __shfl_xor(sa, off); }
        if (lane == 0) {
            beta[(size_t)wave * HH + j] = 2.f / (1.f + expf(-sb));
            const float xg = sa + dt_bias[j];
            const float sp = fmaxf(xg, 0.f) + log1pf(expf(-fabsf(xg)));
            g[(size_t)wave * HH + j] = -expf(A_log[j]) * sp;
        }
    }
}

__global__ __launch_bounds__(256)
void conv_silu_kernel(const float* __restrict__ xin, const float* __restrict__ w,
                      float* __restrict__ y, int C) {
    const int c  = blockIdx.x * 256 + threadIdx.x;
    const int b  = blockIdx.y;
    const int t0 = blockIdx.z * 128;
    const float* xp = xin + (size_t)b * TT * C + c;
    float*       yp = y   + (size_t)b * TT * C + c;
    const float w0 = w[c * 4 + 0], w1 = w[c * 4 + 1], w2 = w[c * 4 + 2], w3 = w[c * 4 + 3];
    float xm3 = (t0 >= 3) ? xp[(size_t)(t0 - 3) * C] : 0.f;
    float xm2 = (t0 >= 2) ? xp[(size_t)(t0 - 2) * C] : 0.f;
    float xm1 = (t0 >= 1) ? xp[(size_t)(t0 - 1) * C] : 0.f;
    for (int t = t0; t < t0 + 128; ++t) {
        const float xc = xp[(size_t)t * C];
        const float u  = fmaf(xm3, w0, fmaf(xm2, w1, fmaf(xm1, w2, xc * w3)));
        yp[(size_t)t * C] = u / (1.f + expf(-u));
        xm3 = xm2; xm2 = xm1; xm1 = xc;
    }
}

__global__ __launch_bounds__(256)
void l2norm_kernel(float* __restrict__ p, float scale) {
    const int row  = (blockIdx.x * 256 + threadIdx.x) >> 6;
    const int lane = threadIdx.x & 63;
    float* r = p + (size_t)row * 64;
    const float v = r[lane];
    float ss = v * v;
#pragma unroll
    for (int off = 32; off > 0; off >>= 1) ss += __shfl_xor(ss, off);
    r[lane] = v * rsqrtf(ss + 1e-6f) * scale;
}

__global__ __launch_bounds__(256)
void onorm_kernel(float* __restrict__ o, const float* __restrict__ gate,
                  const float* __restrict__ w) {
    const int row  = (blockIdx.x * 256 + threadIdx.x) >> 6;
    const int lane = threadIdx.x & 63;
    float*       op = o    + (size_t)row * DVV;
    const float* gp = gate + (size_t)row * DVV;
    const float v0 = op[lane], v1 = op[lane + 64];
    float ss = fmaf(v0, v0, v1 * v1);
#pragma unroll
    for (int off = 32; off > 0; off >>= 1) ss += __shfl_xor(ss, off);
    const float r  = rsqrtf(ss * (1.0f / DVV) + 1e-5f);
    const float g0 = gp[lane], g1 = gp[lane + 64];
    op[lane]      = v0 * r * w[lane]      * (g0 / (1.f + expf(-g0)));
    op[lane + 64] = v1 * r * w[lane + 64] * (g1 / (1.f + expf(-g1)));
}

// ---------------- bf16x3 MFMA GEMM (unchanged from v4/v5) ----------------
template <int EPI>   // 0: C=acc ; 1: C=res+scale[n]*acc ; 2: C=relu(acc)^2
__global__ __launch_bounds__(256)
void gemm_bf3(const float* __restrict__ A, const float* __restrict__ Bw,
              float* __restrict__ C, const float* __restrict__ res,
              const float* __restrict__ scale, const float* __restrict__ rs,
              int M, int N, int K) {
    __shared__ unsigned short Ah[128][40];
    __shared__ unsigned short Al[128][40];
    __shared__ unsigned short Bh[128][40];
    __shared__ unsigned short Bl[128][40];

    const int tid = threadIdx.x;
    const int bm = blockIdx.x * 128;
    const int bn = blockIdx.y * 128;

    const int srow = tid >> 1;
    const int skq  = (tid & 1) * 16;
    const float arow = rs ? rs[bm + srow] : 1.0f;
    const float* Ap = A + (size_t)(bm + srow) * K + skq;
    const int brow_g = bn + srow;
    const float* Bp = Bw + (size_t)(brow_g < N ? brow_g : N - 1) * K + skq;

    const int lane = tid & 63, wid = tid >> 6;
    const int wr = wid >> 1, wc = wid & 1;
    const int lm = lane & 15, kg = lane >> 4;

    f32x4 acc[4][4];
#pragma unroll
    for (int i = 0; i < 4; ++i)
#pragma unroll
        for (int j = 0; j < 4; ++j) acc[i][j] = (f32x4){0.f, 0.f, 0.f, 0.f};

    const int nk = K / 32;
    float4 ar0, ar1, ar2, ar3, br0, br1, br2, br3;
    ar0 = *(const float4*)(Ap + 0);  ar1 = *(const float4*)(Ap + 4);
    ar2 = *(const float4*)(Ap + 8);  ar3 = *(const float4*)(Ap + 12);
    br0 = *(const float4*)(Bp + 0);  br1 = *(const float4*)(Bp + 4);
    br2 = *(const float4*)(Bp + 8);  br3 = *(const float4*)(Bp + 12);

    for (int ks = 0; ks < nk; ++ks) {
        __syncthreads();
        {
            float f0, f1, f2, f3, f4, f5, f6, f7;
            ushort8 h, l;
            f0 = ar0.x * arow; f1 = ar0.y * arow; f2 = ar0.z * arow; f3 = ar0.w * arow;
            f4 = ar1.x * arow; f5 = ar1.y * arow; f6 = ar1.z * arow; f7 = ar1.w * arow;
            h[0]=f2bf(f0); h[1]=f2bf(f1); h[2]=f2bf(f2); h[3]=f2bf(f3);
            h[4]=f2bf(f4); h[5]=f2bf(f5); h[6]=f2bf(f6); h[7]=f2bf(f7);
            l[0]=f2bf(f0-bf2f(h[0])); l[1]=f2bf(f1-bf2f(h[1])); l[2]=f2bf(f2-bf2f(h[2])); l[3]=f2bf(f3-bf2f(h[3]));
            l[4]=f2bf(f4-bf2f(h[4])); l[5]=f2bf(f5-bf2f(h[5])); l[6]=f2bf(f6-bf2f(h[6])); l[7]=f2bf(f7-bf2f(h[7]));
            *(ushort8*)&Ah[srow][skq] = h; *(ushort8*)&Al[srow][skq] = l;
            f0 = ar2.x * arow; f1 = ar2.y * arow; f2 = ar2.z * arow; f3 = ar2.w * arow;
            f4 = ar3.x * arow; f5 = ar3.y * arow; f6 = ar3.z * arow; f7 = ar3.w * arow;
            h[0]=f2bf(f0); h[1]=f2bf(f1); h[2]=f2bf(f2); h[3]=f2bf(f3);
            h[4]=f2bf(f4); h[5]=f2bf(f5); h[6]=f2bf(f6); h[7]=f2bf(f7);
            l[0]=f2bf(f0-bf2f(h[0])); l[1]=f2bf(f1-bf2f(h[1])); l[2]=f2bf(f2-bf2f(h[2])); l[3]=f2bf(f3-bf2f(h[3]));
            l[4]=f2bf(f4-bf2f(h[4])); l[5]=f2bf(f5-bf2f(h[5])); l[6]=f2bf(f6-bf2f(h[6])); l[7]=f2bf(f7-bf2f(h[7]));
            *(ushort8*)&Ah[srow][skq + 8] = h; *(ushort8*)&Al[srow][skq + 8] = l;
            f0 = br0.x; f1 = br0.y; f2 = br0.z; f3 = br0.w;
            f4 = br1.x; f5 = br1.y; f6 = br1.z; f7 = br1.w;
            h[0]=f2bf(f0); h[1]=f2bf(f1); h[2]=f2bf(f2); h[3]=f2bf(f3);
            h[4]=f2bf(f4); h[5]=f2bf(f5); h[6]=f2bf(f6); h[7]=f2bf(f7);
            l[0]=f2bf(f0-bf2f(h[0])); l[1]=f2bf(f1-bf2f(h[1])); l[2]=f2bf(f2-bf2f(h[2])); l[3]=f2bf(f3-bf2f(h[3]));
            l[4]=f2bf(f4-bf2f(h[4])); l[5]=f2bf(f5-bf2f(h[5])); l[6]=f2bf(f6-bf2f(h[6])); l[7]=f2bf(f7-bf2f(h[7]));
            *(ushort8*)&Bh[srow][skq] = h; *(ushort8*)&Bl[srow][skq] = l;
            f0 = br2.x; f1 = br2.y; f2 = br2.z; f3 = br2.w;
            f4 = br3.x; f5 = br3.y; f6 = br3.z; f7 = br3.w;
            h[0]=f2bf(f0); h[1]=f2bf(f1); h[2]=f2bf(f2); h[3]=f2bf(f3);
            h[4]=f2bf(f4); h[5]=f2bf(f5); h[6]=f2bf(f6); h[7]=f2bf(f7);
            l[0]=f2bf(f0-bf2f(h[0])); l[1]=f2bf(f1-bf2f(h[1])); l[2]=f2bf(f2-bf2f(h[2])); l[3]=f2bf(f3-bf2f(h[3]));
            l[4]=f2bf(f4-bf2f(h[4])); l[5]=f2bf(f5-bf2f(h[5])); l[6]=f2bf(f6-bf2f(h[6])); l[7]=f2bf(f7-bf2f(h[7]));
            *(ushort8*)&Bh[srow][skq + 8] = h; *(ushort8*)&Bl[srow][skq + 8] = l;
        }
        __syncthreads();
        if (ks + 1 < nk) {
            const float* ap = Ap + (ks + 1) * 32;
            const float* bp = Bp + (ks + 1) * 32;
            ar0 = *(const float4*)(ap + 0);  ar1 = *(const float4*)(ap + 4);
            ar2 = *(const float4*)(ap + 8);  ar3 = *(const float4*)(ap + 12);
            br0 = *(const float4*)(bp + 0);  br1 = *(const float4*)(bp + 4);
            br2 = *(const float4*)(bp + 8);  br3 = *(const float4*)(bp + 12);
        }
        bf16x8 fah[4], fal[4], fbh[4], fbl[4];
#pragma unroll
        for (int i = 0; i < 4; ++i) {
            fah[i] = *(const bf16x8*)&Ah[wr * 64 + i * 16 + lm][kg * 8];
            fal[i] = *(const bf16x8*)&Al[wr * 64 + i * 16 + lm][kg * 8];
            fbh[i] = *(const bf16x8*)&Bh[wc * 64 + i * 16 + lm][kg * 8];
            fbl[i] = *(const bf16x8*)&Bl[wc * 64 + i * 16 + lm][kg * 8];
        }
#pragma unroll
        for (int mi = 0; mi < 4; ++mi)
#pragma unroll
            for (int ni = 0; ni < 4; ++ni) {
                acc[mi][ni] = __builtin_amdgcn_mfma_f32_16x16x32_bf16(fal[mi], fbh[ni], acc[mi][ni], 0, 0, 0);
                acc[mi][ni] = __builtin_amdgcn_mfma_f32_16x16x32_bf16(fah[mi], fbl[ni], acc[mi][ni], 0, 0, 0);
                acc[mi][ni] = __builtin_amdgcn_mfma_f32_16x16x32_bf16(fah[mi], fbh[ni], acc[mi][ni], 0, 0, 0);
            }
    }

#pragma unroll
    for (int mi = 0; mi < 4; ++mi)
#pragma unroll
        for (int ni = 0; ni < 4; ++ni) {
            const int n = bn + wc * 64 + ni * 16 + lm;
            if (n < N) {
#pragma unroll
                for (int r = 0; r < 4; ++r) {
                    const int m = bm + wr * 64 + mi * 16 + kg * 4 + r;
                    float v = acc[mi][ni][r];
                    if (EPI == 1)      v = res[(size_t)m * N + n] + scale[n] * v;
                    else if (EPI == 2) { const float t = fmaxf(v, 0.f); v = t * t; }
                    C[(size_t)m * N + n] = v;
                }
            }
        }
}

// ---------------- gated delta-rule scan: chunked LDS-staged pipeline ----------
// grid (64,4), 64 threads. Per chunk of 64 steps: k(64x64), q(64x64), v-slice
// (64x32), g, beta staged into LDS via global_load_lds (no register results ->
// compiler cannot sink the prefetch). Double-buffered; staging for chunk c+1 is
// issued in 4 quarter-bursts (<=63 outstanding vmcnt) during chunk c's compute;
// single s_waitcnt vmcnt(0) at the chunk boundary. Consumer reads are LDS
// broadcasts (~120 cyc latency, hidden by depth-1 register prefetch which the
// compiler schedules well for ds_read). Math identical to v4/v5 (folded decay).
#define CHK 64
__global__ __launch_bounds__(64)
void scan_kernel(const float* __restrict__ q, const float* __restrict__ k,
                 const float* __restrict__ v, const float* __restrict__ g,
                 const float* __restrict__ beta, float* __restrict__ o) {
    __shared__ float klds[2][CHK][64];   // [buf][step][row]
    __shared__ float qlds[2][CHK][64];
    __shared__ float vlds[2][CHK][32];   // v slice for this column group
    __shared__ float glds[2][CHK];
    __shared__ float blds[2][CHK];

    const int bh   = blockIdx.x;
    const int cg   = blockIdx.y;
    const int b    = bh >> 3, hh = bh & 7;
    const int lane = threadIdx.x;
    const int half = lane >> 5;
    const int col  = cg * 32 + (lane & 31);

    const float* kb = k + ((size_t)b * TT * HH + hh) * DKK;          // row t: +t*512
    const float* qb = q + ((size_t)b * TT * HH + hh) * DKK;
    const float* vs = v + (size_t)b * TT * VD + hh * DVV + cg * 32;  // slice: row t: +t*1024
    const float* gp = g    + (size_t)b * TT * HH + hh;
    const float* bp = beta + (size_t)b * TT * HH + hh;
    float*       op = o + (size_t)b * TT * VD + hh * DVV + col;

    float S[32];
#pragma unroll
    for (int i = 0; i < 32; ++i) S[i] = 0.f;

    // ---- stage one quarter (16 steps of k/q, 16 steps of v, g/b on qi==0) ----
    auto stage_q = [&](int c0, int buf, int qi) {
        const int r0 = qi * 16;
#pragma unroll
        for (int r = r0; r < r0 + 16; ++r) {
            gload_lds4(kb + (size_t)(c0 + r) * KD + lane, &klds[buf][r][0]);
            gload_lds4(qb + (size_t)(c0 + r) * KD + lane, &qlds[buf][r][0]);
        }
#pragma unroll
        for (int j = qi * 8; j < qi * 8 + 8; ++j) {   // 2 v-rows per instr
            gload_lds4(vs + (size_t)(c0 + 2 * j + half) * VD + (lane & 31),
                       &vlds[buf][2 * j][0]);
        }
        if (qi == 0) {
            gload_lds4(gp + (size_t)(c0 + lane) * HH, &glds[buf][0]);
            gload_lds4(bp + (size_t)(c0 + lane) * HH, &blds[buf][0]);
        }
    };

    // prologue: stage chunk 0 fully, wait.
#pragma unroll
    for (int qi = 0; qi < 4; ++qi) stage_q(0, 0, qi);
    asm volatile("s_waitcnt vmcnt(0)" ::: "memory");
    __builtin_amdgcn_sched_barrier(0);

    int buf = 0;
    for (int c0 = 0; c0 < TT; c0 += CHK, buf ^= 1) {
        const bool more = (c0 + CHK < TT);

        // preload step 0 of this chunk from LDS
        float4 ck[8], cq[8];
#pragma unroll
        for (int i = 0; i < 8; ++i) {
            ck[i] = *(const float4*)&klds[buf][0][half * 32 + i * 4];
            cq[i] = *(const float4*)&qlds[buf][0][half * 32 + i * 4];
        }
        float cv = vlds[buf][0][lane & 31];
        float ce = expf(glds[buf][0]);
        float cb = blds[buf][0];

        for (int t = 0; t < CHK; ++t) {
            if (more && (t & 15) == 0) stage_q(c0 + CHK, buf ^ 1, t >> 4);

            const int tn = (t + 1 < CHK) ? t + 1 : t;   // depth-1 LDS prefetch
            float4 nk[8], nq[8];
#pragma unroll
            for (int i = 0; i < 8; ++i) {
                nk[i] = *(const float4*)&klds[buf][tn][half * 32 + i * 4];
                nq[i] = *(const float4*)&qlds[buf][tn][half * 32 + i * 4];
            }
            const float nv = vlds[buf][tn][lane & 31];
            const float ne = expf(glds[buf][tn]);
            const float nb = blds[buf][tn];

            // dot = k^T S_old (decay folded into vres / S-update)
            float d0 = 0.f, d1 = 0.f, d2 = 0.f, d3 = 0.f;
#pragma unroll
            for (int i = 0; i < 8; ++i) {
                d0 = fmaf(S[4*i+0], ck[i].x, d0);
                d1 = fmaf(S[4*i+1], ck[i].y, d1);
                d2 = fmaf(S[4*i+2], ck[i].z, d2);
                d3 = fmaf(S[4*i+3], ck[i].w, d3);
            }
            float dot = (d0 + d1) + (d2 + d3);
            dot += __shfl_xor(dot, 32);
            const float e = ce;
            const float vres = fmaf(-e, dot * cb, cv * cb);   // (v - e*dot)*beta
            float o0 = 0.f, o1 = 0.f, o2 = 0.f, o3 = 0.f;
#pragma unroll
            for (int i = 0; i < 8; ++i) {   // S = e*S + k*vres ; out = q^T S
                S[4*i+0] = fmaf(S[4*i+0], e, ck[i].x * vres); o0 = fmaf(S[4*i+0], cq[i].x, o0);
                S[4*i+1] = fmaf(S[4*i+1], e, ck[i].y * vres); o1 = fmaf(S[4*i+1], cq[i].y, o1);
                S[4*i+2] = fmaf(S[4*i+2], e, ck[i].z * vres); o2 = fmaf(S[4*i+2], cq[i].z, o2);
                S[4*i+3] = fmaf(S[4*i+3], e, ck[i].w * vres); o3 = fmaf(S[4*i+3], cq[i].w, o3);
            }
            float outv = (o0 + o1) + (o2 + o3);
            outv += __shfl_xor(outv, 32);
            if (lane < 32) op[(size_t)(c0 + t) * VD] = outv;

#pragma unroll
            for (int i = 0; i < 8; ++i) { ck[i] = nk[i]; cq[i] = nq[i]; }
            cv = nv; ce = ne; cb = nb;
        }

        // chunk boundary: next chunk's staged loads must have landed
        asm volatile("s_waitcnt vmcnt(0)" ::: "memory");
        __builtin_amdgcn_sched_barrier(0);
    }
}

// ---------------- launch ----------------
extern "C" void kernel_launch(void* const* d_in, const int* in_sizes, int n_in,
                              void* d_out, int out_size, void* d_ws, size_t ws_size,
                              hipStream_t stream) {
    const float* x        = (const float*)d_in[0];
    const float* Wq       = (const float*)d_in[1];
    const float* Wk       = (const float*)d_in[2];
    const float* Wv       = (const float*)d_in[3];
    const float* Wb       = (const float*)d_in[4];
    const float* Wa       = (const float*)d_in[5];
    const float* Wg       = (const float*)d_in[6];
    const float* Wo       = (const float*)d_in[7];
    const float* conv_q   = (const float*)d_in[8];
    const float* conv_k   = (const float*)d_in[9];
    const float* conv_v   = (const float*)d_in[10];
    const float* A_log    = (const float*)d_in[11];
    const float* dt_bias  = (const float*)d_in[12];
    const float* o_norm_w = (const float*)d_in[13];
    const float* W_fc     = (const float*)d_in[14];
    const float* W_proj   = (const float*)d_in[15];
    const float* gdn      = (const float*)d_in[16];
    const float* mlps     = (const float*)d_in[17];
    float* out = (float*)d_out;
    float* ws  = (float*)d_ws;

    if (ws_size < WS_FLOATS * sizeof(float)) {
        hipMemsetAsync(d_out, 0, (size_t)out_size * sizeof(float), stream);
        return;
    }

    float* r1    = ws + OFF_R1;
    float* r2    = ws + OFF_R2;
    float* betab = ws + OFF_BETA;
    float* gbuf  = ws + OFF_G;
    float* ppre  = ws + OFF_PPRE;
    float* qbuf  = ws + OFF_QBUF;
    float* kbuf  = ws + OFF_KBUF;
    float* vbuf  = ws + OFF_VBUF;
    float* obuf  = ws + OFF_PPRE;
    float* gateb = ws + OFF_QBUF;
    float* xmid  = ws + OFF_VBUF;
    float* m2    = ws + OFF_PPRE;

    rms_scale_kernel<<<MTOK, 256, 0, stream>>>(x, r1, 1e-6f);
    proj_bg_kernel<<<MTOK / 4, 256, 0, stream>>>(x, r1, Wb, Wa, A_log, dt_bias, betab, gbuf);

    dim3 gqk(MTOK / 128, KD / 128);
    dim3 gvv(MTOK / 128, VD / 128);
    gemm_bf3<0><<<gqk, 256, 0, stream>>>(x, Wq, ppre, nullptr, nullptr, r1, MTOK, KD, DD);
    conv_silu_kernel<<<dim3(KD / 256, BB, TT / 128), 256, 0, stream>>>(ppre, conv_q, qbuf, KD);
    gemm_bf3<0><<<gqk, 256, 0, stream>>>(x, Wk, ppre, nullptr, nullptr, r1, MTOK, KD, DD);
    conv_silu_kernel<<<dim3(KD / 256, BB, TT / 128), 256, 0, stream>>>(ppre, conv_k, kbuf, KD);
    gemm_bf3<0><<<gvv, 256, 0, stream>>>(x, Wv, ppre, nullptr, nullptr, r1, MTOK, VD, DD);
    conv_silu_kernel<<<dim3(VD / 256, BB, TT / 128), 256, 0, stream>>>(ppre, conv_v, vbuf, VD);

    l2norm_kernel<<<(MTOK * HH) / 4, 256, 0, stream>>>(qbuf, 0.125f);
    l2norm_kernel<<<(MTOK * HH) / 4, 256, 0, stream>>>(kbuf, 1.f);

    scan_kernel<<<dim3(64, 4), 64, 0, stream>>>(qbuf, kbuf, vbuf, gbuf, betab, obuf);

    gemm_bf3<0><<<gvv, 256, 0, stream>>>(x, Wg, gateb, nullptr, nullptr, r1, MTOK, VD, DD);
    onorm_kernel<<<(MTOK * HH) / 4, 256, 0, stream>>>(obuf, gateb, o_norm_w);

    dim3 go(MTOK / 128, (DD + 127) / 128);
    gemm_bf3<1><<<go, 256, 0, stream>>>(obuf, Wo, xmid, x, gdn, nullptr, MTOK, DD, VD);

    rms_scale_kernel<<<MTOK, 256, 0, stream>>>(xmid, r2, 1e-6f);
    dim3 gf(MTOK / 128, (HIDD + 127) / 128);
    gemm_bf3<2><<<gf, 256, 0, stream>>>(xmid, W_fc, m2, nullptr, nullptr, r2, MTOK, HIDD, DD);
    dim3 gpj(MTOK / 128, (DD + 127) / 128);
    gemm_bf3<1><<<gpj, 256, 0, stream>>>(m2, W_proj, out, xmid, mlps, nullptr, MTOK, DD, HIDD);

    (void)in_sizes; (void)n_in; (void)ws_size;
}